// Round 1
// baseline (6846.963 us; speedup 1.0000x reference)
//
#include <hip/hip_runtime.h>
#include <hip/hip_bf16.h>

typedef __bf16 bf16;
typedef __attribute__((ext_vector_type(8))) __bf16 bf16x8;
typedef __attribute__((ext_vector_type(4))) float f32x4;

#define H_IN 1342
#define HC   256
#define TT   128
#define BB   128

static __device__ __forceinline__ f32x4 mfma16(bf16x8 a, bf16x8 b, f32x4 c) {
    return __builtin_amdgcn_mfma_f32_16x16x32_bf16(a, b, c, 0, 0, 0);
}
static __device__ __forceinline__ float sigf(float x) {
    return 1.f / (1.f + __expf(-x));
}
static __device__ __forceinline__ float tanhfast(float x) {
    return 2.f / (1.f + __expf(-2.f * x)) - 1.f;
}

// ---------------------------------------------------------------------------
// Weight packing into MFMA B-fragment order.
// Layer 0 (gh only, K=256, 48 n-tiles): frag(nt,kt) elems at (nt*8+kt)*512,
//   value = w_hh0[n][k], n = nt*16+(lane&15), k = kt*32+(lane>>4)*8+j.
// Layers 1,2 (base 196608 + li*393216):
//   rz   (nt in [0,32), K=512): (nt*16+kt)*512 ; k<256 -> w_ih, else w_hh
//   xn   (+262144, nt' in [0,16), K=256): (nt'*8+kt)*512 ; w_ih[512+..]
//   hn   (+327680, nt' in [0,16), K=256): (nt'*8+kt)*512 ; w_hh[512+..]
// Bias pack (fp32, 2816): L0: b_hh0[768]; L1/L2 @768/@1792: [0,512)=bih+bhh,
//   [512,768)=bih[512+j], [768,1024)=bhh[512+j].
// ---------------------------------------------------------------------------
__global__ void prep_pack(const float* __restrict__ whh0,
                          const float* __restrict__ wih1, const float* __restrict__ whh1,
                          const float* __restrict__ wih2, const float* __restrict__ whh2,
                          const float* __restrict__ bhh0,
                          const float* __restrict__ bih1, const float* __restrict__ bhh1,
                          const float* __restrict__ bih2, const float* __restrict__ bhh2,
                          bf16* __restrict__ Wp, float* __restrict__ bp)
{
    int idx = blockIdx.x * blockDim.x + threadIdx.x;
    if (idx < 983040) {
        float val;
        if (idx < 196608) {
            int f = idx >> 9, q = idx & 511;
            int lane = q >> 3, j = q & 7;
            int nt = f >> 3, kt = f & 7;
            int n = nt * 16 + (lane & 15);
            int k = kt * 32 + (lane >> 4) * 8 + j;
            val = whh0[n * 256 + k];
        } else {
            int r = idx - 196608;
            int li = r / 393216; r -= li * 393216;
            const float* wih = li ? wih2 : wih1;
            const float* whh = li ? whh2 : whh1;
            if (r < 262144) {
                int f = r >> 9, q = r & 511;
                int lane = q >> 3, j = q & 7;
                int nt = f >> 4, kt = f & 15;
                int n = nt * 16 + (lane & 15);
                int k = kt * 32 + (lane >> 4) * 8 + j;
                val = (k < 256) ? wih[n * 256 + k] : whh[n * 256 + (k - 256)];
            } else if (r < 327680) {
                int rr = r - 262144;
                int f = rr >> 9, q = rr & 511;
                int lane = q >> 3, j = q & 7;
                int nt = f >> 3, kt = f & 7;
                int n = 512 + nt * 16 + (lane & 15);
                int k = kt * 32 + (lane >> 4) * 8 + j;
                val = wih[n * 256 + k];
            } else {
                int rr = r - 327680;
                int f = rr >> 9, q = rr & 511;
                int lane = q >> 3, j = q & 7;
                int nt = f >> 3, kt = f & 7;
                int n = 512 + nt * 16 + (lane & 15);
                int k = kt * 32 + (lane >> 4) * 8 + j;
                val = whh[n * 256 + k];
            }
        }
        Wp[idx] = (bf16)val;
    } else if (idx < 985856) {
        int c = idx - 983040;
        float v;
        if (c < 768) {
            v = bhh0[c];
        } else if (c < 1792) {
            int q = c - 768;
            v = (q < 512) ? (bih1[q] + bhh1[q]) : (q < 768) ? bih1[q] : bhh1[q - 256];
        } else {
            int q = c - 1792;
            v = (q < 512) ? (bih2[q] + bhh2[q]) : (q < 768) ? bih2[q] : bhh2[q - 256];
        }
        bp[c] = v;
    }
}

// ---------------------------------------------------------------------------
// gx0[t][b][g] = sum_i X[b][t][i] * w_ih0[g][i] + b_ih0[g]
// GEMM: M=16384 (rm = b*128+t), N=768, K=1342 (padded to 1344), bf16 MFMA.
// Tile 128x256, 8 waves: wave w owns m-tile w (16 rows) x 16 n-tiles.
// ---------------------------------------------------------------------------
__global__ __launch_bounds__(512) void gemm_gx0(const float* __restrict__ X,
                                                const float* __restrict__ W,
                                                const float* __restrict__ bih0,
                                                float* __restrict__ gx0)
{
    __shared__ bf16 As[128][40];   // +8 pad -> conflict-free b128 frag reads
    __shared__ bf16 Bs[256][40];
    const int tid  = threadIdx.x;
    const int lane = tid & 63;
    const int w    = tid >> 6;
    const int cl   = lane & 15;
    const int lh   = lane >> 4;
    const int rm0  = blockIdx.x * 128;
    const int n0   = blockIdx.y * 256;

    f32x4 acc[16];
#pragma unroll
    for (int i = 0; i < 16; ++i) acc[i] = (f32x4){0.f, 0.f, 0.f, 0.f};

    for (int kt = 0; kt < 42; ++kt) {
        const int k0 = kt * 32;
        {   // stage A: 128 rows x 32 k ; thread: row=tid>>2, 8 floats
            int row = tid >> 2;
            int c   = (tid & 3) * 8;
            const float* src = X + (size_t)(rm0 + row) * H_IN + (k0 + c);
            bf16x8 pk;
            if (k0 + c + 8 <= H_IN) {
                const float2* s2 = (const float2*)src;
                float2 v0 = s2[0], v1 = s2[1], v2 = s2[2], v3 = s2[3];
                pk[0] = (bf16)v0.x; pk[1] = (bf16)v0.y; pk[2] = (bf16)v1.x; pk[3] = (bf16)v1.y;
                pk[4] = (bf16)v2.x; pk[5] = (bf16)v2.y; pk[6] = (bf16)v3.x; pk[7] = (bf16)v3.y;
            } else {
#pragma unroll
                for (int i = 0; i < 8; ++i)
                    pk[i] = (bf16)((k0 + c + i < H_IN) ? src[i] : 0.f);
            }
            *(bf16x8*)&As[row][c] = pk;
        }
        {   // stage B: 256 rows (n) x 32 k ; thread: row=tid>>1, 16 floats
            int row = tid >> 1;
            int c   = (tid & 1) * 16;
            const float* src = W + (size_t)(n0 + row) * H_IN + (k0 + c);
#pragma unroll
            for (int h = 0; h < 2; ++h) {
                const float* s = src + h * 8;
                bf16x8 pk;
                if (k0 + c + h * 8 + 8 <= H_IN) {
                    const float2* s2 = (const float2*)s;
                    float2 v0 = s2[0], v1 = s2[1], v2 = s2[2], v3 = s2[3];
                    pk[0] = (bf16)v0.x; pk[1] = (bf16)v0.y; pk[2] = (bf16)v1.x; pk[3] = (bf16)v1.y;
                    pk[4] = (bf16)v2.x; pk[5] = (bf16)v2.y; pk[6] = (bf16)v3.x; pk[7] = (bf16)v3.y;
                } else {
#pragma unroll
                    for (int i = 0; i < 8; ++i)
                        pk[i] = (bf16)((k0 + c + h * 8 + i < H_IN) ? s[i] : 0.f);
                }
                *(bf16x8*)&Bs[row][c + h * 8] = pk;
            }
        }
        __syncthreads();
        bf16x8 a = *(const bf16x8*)&As[w * 16 + cl][lh * 8];
#pragma unroll
        for (int nt = 0; nt < 16; ++nt) {
            bf16x8 b = *(const bf16x8*)&Bs[nt * 16 + cl][lh * 8];
            acc[nt] = mfma16(a, b, acc[nt]);
        }
        __syncthreads();
    }
    // epilogue: D row = 4*lh + r, col = nt*16 + cl
#pragma unroll
    for (int nt = 0; nt < 16; ++nt) {
#pragma unroll
        for (int r = 0; r < 4; ++r) {
            int rm  = rm0 + w * 16 + 4 * lh + r;
            int col = n0 + nt * 16 + cl;
            int b = rm >> 7, t = rm & 127;
            gx0[((size_t)t * BB + b) * 768 + col] = acc[nt][r] + bih0[col];
        }
    }
}

// ---------------------------------------------------------------------------
// Persistent GRU: 8 blocks x 512 threads; block owns 16 batch rows.
// Wave w owns col-tiles jt in {2w, 2w+1}; gates computed fully in C-layout.
// ---------------------------------------------------------------------------
template <bool HASNEXT>
static __device__ __forceinline__ void layer_step(
    bf16 (*Aself)[520], bf16 (*Anext)[520],
    const bf16* __restrict__ WL, const float* __restrict__ bsL,
    float hr[2][4], int w, int cl, int lh)
{
    f32x4 cr[2], cz[2], cx[2], ch[2];
#pragma unroll
    for (int i = 0; i < 2; ++i) {
        cr[i] = (f32x4){0.f,0.f,0.f,0.f}; cz[i] = (f32x4){0.f,0.f,0.f,0.f};
        cx[i] = (f32x4){0.f,0.f,0.f,0.f}; ch[i] = (f32x4){0.f,0.f,0.f,0.f};
    }
    const int lane = lh * 16 + cl;
#pragma unroll
    for (int kk = 0; kk < 16; ++kk) {
        bf16x8 a = *(const bf16x8*)&Aself[cl][kk * 32 + lh * 8];
#pragma unroll
        for (int ji = 0; ji < 2; ++ji) {
            const int jt = 2 * w + ji;
            bf16x8 br = *(const bf16x8*)(WL + (size_t)((jt * 16 + kk) * 512) + lane * 8);
            bf16x8 bz = *(const bf16x8*)(WL + (size_t)(((16 + jt) * 16 + kk) * 512) + lane * 8);
            cr[ji] = mfma16(a, br, cr[ji]);
            cz[ji] = mfma16(a, bz, cz[ji]);
            if (kk < 8) {
                bf16x8 bx = *(const bf16x8*)(WL + (size_t)(262144 + (jt * 8 + kk) * 512) + lane * 8);
                cx[ji] = mfma16(a, bx, cx[ji]);
            } else {
                bf16x8 bh = *(const bf16x8*)(WL + (size_t)(327680 + (jt * 8 + kk - 8) * 512) + lane * 8);
                ch[ji] = mfma16(a, bh, ch[ji]);
            }
        }
    }
    __syncthreads();   // all waves done reading Aself
#pragma unroll
    for (int ji = 0; ji < 2; ++ji) {
        const int col = (2 * w + ji) * 16 + cl;
#pragma unroll
        for (int r = 0; r < 4; ++r) {
            const int m = 4 * lh + r;
            float rr = sigf(cr[ji][r] + bsL[col]);
            float zz = sigf(cz[ji][r] + bsL[256 + col]);
            float nn = tanhfast(cx[ji][r] + bsL[512 + col] + rr * (ch[ji][r] + bsL[768 + col]));
            float hnew = (1.f - zz) * nn + zz * hr[ji][r];
            hr[ji][r] = hnew;
            bf16 hb = (bf16)hnew;
            Aself[m][256 + col] = hb;
            if constexpr (HASNEXT) Anext[m][col] = hb;
        }
    }
    __syncthreads();   // writes visible before next GEMM
}

__global__ __launch_bounds__(512) void gru_rnn(
    const float* __restrict__ gx0,    // [T][B][768]
    const bf16*  __restrict__ Wp,
    const float* __restrict__ bp,
    const float* __restrict__ hidden, // [3][128][256]
    float* __restrict__ hnf)          // [128][768]
{
    __shared__ bf16 A0[16][264];      // h0 (bf16), +8 pad
    __shared__ bf16 A1[16][520];      // [y0 | h1]
    __shared__ bf16 A2[16][520];      // [y1 | h2]
    __shared__ float bias[2816];

    const int tid  = threadIdx.x;
    const int lane = tid & 63;
    const int w    = tid >> 6;        // 0..7
    const int cl   = lane & 15;
    const int lh   = lane >> 4;
    const int b0   = blockIdx.x * 16;

    for (int i = tid; i < 2816; i += 512) bias[i] = bp[i];

    float h0r[2][4], h1r[2][4], h2r[2][4];
#pragma unroll
    for (int ji = 0; ji < 2; ++ji) {
        const int col = (2 * w + ji) * 16 + cl;
#pragma unroll
        for (int r = 0; r < 4; ++r) {
            const int m = 4 * lh + r;
            float v0 = hidden[(0 * BB + b0 + m) * 256 + col];
            float v1 = hidden[(1 * BB + b0 + m) * 256 + col];
            float v2 = hidden[(2 * BB + b0 + m) * 256 + col];
            h0r[ji][r] = v0; h1r[ji][r] = v1; h2r[ji][r] = v2;
            A0[m][col]       = (bf16)v0;
            A1[m][256 + col] = (bf16)v1;
            A2[m][256 + col] = (bf16)v2;
        }
    }
    __syncthreads();

    const bf16* WL0 = Wp;
    const bf16* WL1 = Wp + 196608;
    const bf16* WL2 = Wp + 589824;
    const float* bs1 = bias + 768;
    const float* bs2 = bias + 1792;

    for (int t = 0; t < TT; ++t) {
        // prefetch gx0 for layer-0 gates (hidden under GEMM0)
        float gxr[2][4], gxz[2][4], gxn[2][4];
#pragma unroll
        for (int ji = 0; ji < 2; ++ji) {
            const int col = (2 * w + ji) * 16 + cl;
#pragma unroll
            for (int r = 0; r < 4; ++r) {
                const int m = 4 * lh + r;
                const float* g = gx0 + ((size_t)t * BB + b0 + m) * 768;
                gxr[ji][r] = g[col];
                gxz[ji][r] = g[256 + col];
                gxn[ji][r] = g[512 + col];
            }
        }
        // ---- layer 0 GEMM: gh0 = A0[16x256] * W0[256x768] ----
        f32x4 c_r[2], c_z[2], c_n[2];
#pragma unroll
        for (int i = 0; i < 2; ++i) {
            c_r[i] = (f32x4){0.f,0.f,0.f,0.f};
            c_z[i] = (f32x4){0.f,0.f,0.f,0.f};
            c_n[i] = (f32x4){0.f,0.f,0.f,0.f};
        }
#pragma unroll
        for (int kk = 0; kk < 8; ++kk) {
            bf16x8 a = *(const bf16x8*)&A0[cl][kk * 32 + lh * 8];
#pragma unroll
            for (int ji = 0; ji < 2; ++ji) {
                const int jt = 2 * w + ji;
                bf16x8 br = *(const bf16x8*)(WL0 + (size_t)(( jt       * 8 + kk) * 512) + lane * 8);
                bf16x8 bz = *(const bf16x8*)(WL0 + (size_t)(((16 + jt) * 8 + kk) * 512) + lane * 8);
                bf16x8 bn = *(const bf16x8*)(WL0 + (size_t)(((32 + jt) * 8 + kk) * 512) + lane * 8);
                c_r[ji] = mfma16(a, br, c_r[ji]);
                c_z[ji] = mfma16(a, bz, c_z[ji]);
                c_n[ji] = mfma16(a, bn, c_n[ji]);
            }
        }
        __syncthreads();
        // ---- layer 0 gates ----
#pragma unroll
        for (int ji = 0; ji < 2; ++ji) {
            const int col = (2 * w + ji) * 16 + cl;
#pragma unroll
            for (int r = 0; r < 4; ++r) {
                const int m = 4 * lh + r;
                float rr = sigf(gxr[ji][r] + c_r[ji][r] + bias[col]);
                float zz = sigf(gxz[ji][r] + c_z[ji][r] + bias[256 + col]);
                float nn = tanhfast(gxn[ji][r] + rr * (c_n[ji][r] + bias[512 + col]));
                float hnew = (1.f - zz) * nn + zz * h0r[ji][r];
                h0r[ji][r] = hnew;
                bf16 hb = (bf16)hnew;
                A0[m][col] = hb;   // next step's gh0 input
                A1[m][col] = hb;   // layer-1 y input
            }
        }
        __syncthreads();
        // ---- layers 1, 2 ----
        layer_step<true >(A1, A2, WL1, bs1, h1r, w, cl, lh);
        layer_step<false>(A2, A2, WL2, bs2, h2r, w, cl, lh);
    }

    // write final hidden states: hnf[b][l*256 + col]
#pragma unroll
    for (int ji = 0; ji < 2; ++ji) {
        const int col = (2 * w + ji) * 16 + cl;
#pragma unroll
        for (int r = 0; r < 4; ++r) {
            const int m = 4 * lh + r;
            float* dst = hnf + (size_t)(b0 + m) * 768;
            dst[col]       = h0r[ji][r];
            dst[256 + col] = h1r[ji][r];
            dst[512 + col] = h2r[ji][r];
        }
    }
}

// ---------------------------------------------------------------------------
// out[b][i] = fc_b[i] + dot(fc_w[i], hn[b])   (one block per b)
// ---------------------------------------------------------------------------
__global__ __launch_bounds__(256) void fc_out(const float* __restrict__ hn,
                                              const float* __restrict__ fcw,
                                              const float* __restrict__ fcb,
                                              float* __restrict__ out)
{
    __shared__ float hs[768];
    const int b = blockIdx.x;
    for (int i = threadIdx.x; i < 768; i += 256) hs[i] = hn[(size_t)b * 768 + i];
    __syncthreads();
    for (int i = threadIdx.x; i < H_IN; i += 256) {
        const float4* wr = (const float4*)(fcw + (size_t)i * 768);
        float a0 = 0.f, a1 = 0.f, a2 = 0.f, a3 = 0.f;
#pragma unroll 4
        for (int c = 0; c < 192; ++c) {
            float4 wv = wr[c];
            const float* h4 = &hs[c * 4];
            a0 += wv.x * h4[0]; a1 += wv.y * h4[1];
            a2 += wv.z * h4[2]; a3 += wv.w * h4[3];
        }
        out[(size_t)b * H_IN + i] = fcb[i] + a0 + a1 + a2 + a3;
    }
}

extern "C" void kernel_launch(void* const* d_in, const int* in_sizes, int n_in,
                              void* d_out, int out_size, void* d_ws, size_t ws_size,
                              hipStream_t stream) {
    const float* X    = (const float*)d_in[0];
    const float* hid  = (const float*)d_in[1];
    const float* wih0 = (const float*)d_in[2];
    const float* whh0 = (const float*)d_in[3];
    const float* bih0 = (const float*)d_in[4];
    const float* bhh0 = (const float*)d_in[5];
    const float* wih1 = (const float*)d_in[6];
    const float* whh1 = (const float*)d_in[7];
    const float* bih1 = (const float*)d_in[8];
    const float* bhh1 = (const float*)d_in[9];
    const float* wih2 = (const float*)d_in[10];
    const float* whh2 = (const float*)d_in[11];
    const float* bih2 = (const float*)d_in[12];
    const float* bhh2 = (const float*)d_in[13];
    const float* fcw  = (const float*)d_in[14];
    const float* fcb  = (const float*)d_in[15];
    float* out = (float*)d_out;

    char* ws = (char*)d_ws;
    float* gx0 = (float*)ws;                                   // 50,331,648 B
    bf16*  Wp  = (bf16*)(ws + 50331648);                       //  1,966,080 B
    float* bp  = (float*)(ws + 50331648 + 1966080);            //     11,264 B
    float* hnf = (float*)(ws + 50331648 + 1966080 + 11264);    //    393,216 B

    prep_pack<<<dim3(1926), dim3(512), 0, stream>>>(whh0, wih1, whh1, wih2, whh2,
                                                    bhh0, bih1, bhh1, bih2, bhh2, Wp, bp);
    gemm_gx0<<<dim3(128, 3), dim3(512), 0, stream>>>(X, wih0, bih0, gx0);
    gru_rnn<<<dim3(8), dim3(512), 0, stream>>>(gx0, Wp, bp, hid, hnf);
    fc_out<<<dim3(128), dim3(256), 0, stream>>>(hnf, fcw, fcb, out);
    // second output: hidden passed through unchanged
    hipMemcpyAsync(out + 171776, hid, 98304 * sizeof(float),
                   hipMemcpyDeviceToDevice, stream);
}

// Round 6
// 2182.612 us; speedup vs baseline: 3.1370x; 3.1370x over previous
//
#include <hip/hip_runtime.h>
#include <hip/hip_bf16.h>

typedef __bf16 bf16;
typedef _Float16 fp16;
typedef __attribute__((ext_vector_type(8))) __bf16 bf16x8;
typedef __attribute__((ext_vector_type(4))) float f32x4;

#define H_IN 1342
#define TT   128
#define BB   128

static __device__ __forceinline__ f32x4 mfma16(bf16x8 a, bf16x8 b, f32x4 c) {
    return __builtin_amdgcn_mfma_f32_16x16x32_bf16(a, b, c, 0, 0, 0);
}
static __device__ __forceinline__ float sigf(float x) {
    return 1.f / (1.f + __expf(-x));
}
static __device__ __forceinline__ float tanhfast(float x) {
    return 2.f / (1.f + __expf(-2.f * x)) - 1.f;
}

// ---------------------------------------------------------------------------
// Pack the three w_hh matrices (768x256 each) into MFMA B-fragment order:
// layer l at Wh + l*196608; frag f = nt*8+kt (nt in [0,48), kt in [0,8)),
// elem (lane, j) = w_hh[nt*16 + (lane&15)][kt*32 + (lane>>4)*8 + j].
// Biases: bp[l*768 + c] = b_hh_l[c]  (b_ih folded into the gx GEMMs).
// ---------------------------------------------------------------------------
__global__ void prep_pack2(const float* __restrict__ whh0,
                           const float* __restrict__ whh1,
                           const float* __restrict__ whh2,
                           const float* __restrict__ bhh0,
                           const float* __restrict__ bhh1,
                           const float* __restrict__ bhh2,
                           bf16* __restrict__ Wh, float* __restrict__ bp)
{
    int idx = blockIdx.x * blockDim.x + threadIdx.x;
    if (idx < 589824) {
        int l = idx / 196608;
        int r = idx - l * 196608;
        const float* w = (l == 0) ? whh0 : (l == 1) ? whh1 : whh2;
        int f = r >> 9, q = r & 511;
        int lane = q >> 3, j = q & 7;
        int nt = f >> 3, kt = f & 7;
        int n = nt * 16 + (lane & 15);
        int k = kt * 32 + (lane >> 4) * 8 + j;
        Wh[idx] = (bf16)w[n * 256 + k];
    } else if (idx < 592128) {
        int c = idx - 589824;            // [0, 2304)
        int l = c / 768, q = c - l * 768;
        const float* b = (l == 0) ? bhh0 : (l == 1) ? bhh1 : bhh2;
        bp[c] = b[q];
    }
}

// ---------------------------------------------------------------------------
// Layer-0 input GEMM: gx[t][b][col] = X[b][t] . w_ih0[col] + b_ih0[col]
// Output split by gate sensitivity: cols [0,512) (r,z) -> fp16, [512,768) -> fp32.
// Round-1-verified structure (M=16384, N=768, K=1342 padded to 1344).
// ---------------------------------------------------------------------------
__global__ __launch_bounds__(512) void gemm_gx0(const float* __restrict__ X,
                                                const float* __restrict__ W,
                                                const float* __restrict__ bih0,
                                                fp16*  __restrict__ gxrz,
                                                float* __restrict__ gxn)
{
    __shared__ bf16 As[128][40];
    __shared__ bf16 Bs[256][40];
    const int tid  = threadIdx.x;
    const int lane = tid & 63;
    const int w    = tid >> 6;
    const int cl   = lane & 15;
    const int lh   = lane >> 4;
    const int rm0  = blockIdx.x * 128;
    const int n0   = blockIdx.y * 256;

    f32x4 acc[16];
#pragma unroll
    for (int i = 0; i < 16; ++i) acc[i] = (f32x4){0.f, 0.f, 0.f, 0.f};

    for (int kt = 0; kt < 42; ++kt) {
        const int k0 = kt * 32;
        {
            int row = tid >> 2;
            int c   = (tid & 3) * 8;
            const float* src = X + (size_t)(rm0 + row) * H_IN + (k0 + c);
            bf16x8 pk;
            if (k0 + c + 8 <= H_IN) {
                const float2* s2 = (const float2*)src;
                float2 v0 = s2[0], v1 = s2[1], v2 = s2[2], v3 = s2[3];
                pk[0] = (bf16)v0.x; pk[1] = (bf16)v0.y; pk[2] = (bf16)v1.x; pk[3] = (bf16)v1.y;
                pk[4] = (bf16)v2.x; pk[5] = (bf16)v2.y; pk[6] = (bf16)v3.x; pk[7] = (bf16)v3.y;
            } else {
#pragma unroll
                for (int i = 0; i < 8; ++i)
                    pk[i] = (bf16)((k0 + c + i < H_IN) ? src[i] : 0.f);
            }
            *(bf16x8*)&As[row][c] = pk;
        }
        {
            int row = tid >> 1;
            int c   = (tid & 1) * 16;
            const float* src = W + (size_t)(n0 + row) * H_IN + (k0 + c);
#pragma unroll
            for (int h = 0; h < 2; ++h) {
                const float* s = src + h * 8;
                bf16x8 pk;
                if (k0 + c + h * 8 + 8 <= H_IN) {
                    const float2* s2 = (const float2*)s;
                    float2 v0 = s2[0], v1 = s2[1], v2 = s2[2], v3 = s2[3];
                    pk[0] = (bf16)v0.x; pk[1] = (bf16)v0.y; pk[2] = (bf16)v1.x; pk[3] = (bf16)v1.y;
                    pk[4] = (bf16)v2.x; pk[5] = (bf16)v2.y; pk[6] = (bf16)v3.x; pk[7] = (bf16)v3.y;
                } else {
#pragma unroll
                    for (int i = 0; i < 8; ++i)
                        pk[i] = (bf16)((k0 + c + h * 8 + i < H_IN) ? s[i] : 0.f);
                }
                *(bf16x8*)&Bs[row][c + h * 8] = pk;
            }
        }
        __syncthreads();
        bf16x8 a = *(const bf16x8*)&As[w * 16 + cl][lh * 8];
#pragma unroll
        for (int nt = 0; nt < 16; ++nt) {
            bf16x8 b = *(const bf16x8*)&Bs[nt * 16 + cl][lh * 8];
            acc[nt] = mfma16(a, b, acc[nt]);
        }
        __syncthreads();
    }
#pragma unroll
    for (int nt = 0; nt < 16; ++nt) {
#pragma unroll
        for (int r = 0; r < 4; ++r) {
            int rm  = rm0 + w * 16 + 4 * lh + r;
            int col = n0 + nt * 16 + cl;
            int b = rm >> 7, t = rm & 127;
            float v = acc[nt][r] + bih0[col];
            size_t ro = (size_t)t * BB + b;
            if (col < 512) gxrz[ro * 512 + col] = (fp16)v;
            else           gxn [ro * 256 + (col - 512)] = v;
        }
    }
}

// ---------------------------------------------------------------------------
// Layers 1/2 input GEMM: gx[t][b][col] = Y[t][b] . w_ih_l[col] + b_ih_l[col]
// Y bf16 [16384][256] (rows = t*128+b), W fp32 [768][256]. K=256 exact.
// ---------------------------------------------------------------------------
__global__ __launch_bounds__(512) void gemm_gxy(const bf16* __restrict__ Y,
                                                const float* __restrict__ W,
                                                const float* __restrict__ bih,
                                                fp16*  __restrict__ gxrz,
                                                float* __restrict__ gxn)
{
    __shared__ bf16 As[128][40];
    __shared__ bf16 Bs[256][40];
    const int tid  = threadIdx.x;
    const int lane = tid & 63;
    const int w    = tid >> 6;
    const int cl   = lane & 15;
    const int lh   = lane >> 4;
    const int rm0  = blockIdx.x * 128;
    const int n0   = blockIdx.y * 256;

    f32x4 acc[16];
#pragma unroll
    for (int i = 0; i < 16; ++i) acc[i] = (f32x4){0.f, 0.f, 0.f, 0.f};

    for (int kt = 0; kt < 8; ++kt) {
        const int k0 = kt * 32;
        {   // A: bf16 direct copy, 8 elems (16B) per thread
            int row = tid >> 2;
            int c   = (tid & 3) * 8;
            *(bf16x8*)&As[row][c] =
                *(const bf16x8*)(Y + (size_t)(rm0 + row) * 256 + k0 + c);
        }
        {   // B: fp32 -> bf16, 16 elems per thread
            int row = tid >> 1;
            int c   = (tid & 1) * 16;
            const float* src = W + (size_t)(n0 + row) * 256 + (k0 + c);
#pragma unroll
            for (int h = 0; h < 2; ++h) {
                const float2* s2 = (const float2*)(src + h * 8);
                float2 v0 = s2[0], v1 = s2[1], v2 = s2[2], v3 = s2[3];
                bf16x8 pk;
                pk[0] = (bf16)v0.x; pk[1] = (bf16)v0.y; pk[2] = (bf16)v1.x; pk[3] = (bf16)v1.y;
                pk[4] = (bf16)v2.x; pk[5] = (bf16)v2.y; pk[6] = (bf16)v3.x; pk[7] = (bf16)v3.y;
                *(bf16x8*)&Bs[row][c + h * 8] = pk;
            }
        }
        __syncthreads();
        bf16x8 a = *(const bf16x8*)&As[w * 16 + cl][lh * 8];
#pragma unroll
        for (int nt = 0; nt < 16; ++nt) {
            bf16x8 b = *(const bf16x8*)&Bs[nt * 16 + cl][lh * 8];
            acc[nt] = mfma16(a, b, acc[nt]);
        }
        __syncthreads();
    }
#pragma unroll
    for (int nt = 0; nt < 16; ++nt) {
#pragma unroll
        for (int r = 0; r < 4; ++r) {
            size_t rm = (size_t)(rm0 + w * 16 + 4 * lh + r);   // = t*128 + b
            int col = n0 + nt * 16 + cl;
            float v = acc[nt][r] + bih[col];
            if (col < 512) gxrz[rm * 512 + col] = (fp16)v;
            else           gxn [rm * 256 + (col - 512)] = v;
        }
    }
}

// ---------------------------------------------------------------------------
// Recurrent layer kernel (uniform for l=0,1,2): gh = h @ w_hh.T via registered
// MFMA B-frags; gates in C-layout. 8 blocks (one per 16-batch group), 512 thr,
// 8 waves x 2 col-tiles — round-1's exact verified structure. h lives in LDS;
// y/gx cross kernel boundaries only (no cross-block sync anywhere).
// ---------------------------------------------------------------------------
__global__ __launch_bounds__(512, 2) void gru_rec(
    const fp16*  __restrict__ gxrz,  // [T*B][512] fp16 (r,z incl. b_ih)
    const float* __restrict__ gxn,   // [T*B][256] fp32 (n incl. b_ih)
    const bf16*  __restrict__ Wh,    // this layer's hh pack (196608)
    const float* __restrict__ bhh,   // this layer's b_hh (768)
    const float* __restrict__ h0,    // hidden + l*128*256
    bf16*  __restrict__ Y,           // [T*B][256] bf16 out
    int writeY,
    float* __restrict__ hnfL)        // hnf + l*256 (stride 768)
{
    __shared__ bf16 Ah[16][264];
    const int tid  = threadIdx.x;
    const int lane = tid & 63;
    const int w    = tid >> 6;
    const int cl   = lane & 15;
    const int lh   = lane >> 4;
    const int g    = blockIdx.x;

    bf16x8 Br[2][8], Bz[2][8], Bn[2][8];
#pragma unroll
    for (int ji = 0; ji < 2; ++ji) {
        const int jt = 2 * w + ji;
#pragma unroll
        for (int kk = 0; kk < 8; ++kk) {
            Br[ji][kk] = *(const bf16x8*)(Wh + (size_t)(( jt       * 8 + kk) * 512) + lane * 8);
            Bz[ji][kk] = *(const bf16x8*)(Wh + (size_t)(((16 + jt) * 8 + kk) * 512) + lane * 8);
            Bn[ji][kk] = *(const bf16x8*)(Wh + (size_t)(((32 + jt) * 8 + kk) * 512) + lane * 8);
        }
    }

    float hprev[2][4];
    float bR[2], bZ[2], bN[2];
#pragma unroll
    for (int ji = 0; ji < 2; ++ji) {
        const int col = (2 * w + ji) * 16 + cl;
        bR[ji] = bhh[col]; bZ[ji] = bhh[256 + col]; bN[ji] = bhh[512 + col];
#pragma unroll
        for (int r = 0; r < 4; ++r) {
            const int m = 4 * lh + r;
            float v = h0[(size_t)(g * 16 + m) * 256 + col];
            hprev[ji][r] = v;
            Ah[m][col] = (bf16)v;
        }
    }
    __syncthreads();

    for (int t = 0; t < TT; ++t) {
        f32x4 cr[2], cz[2], cn[2];
#pragma unroll
        for (int i = 0; i < 2; ++i) {
            cr[i] = (f32x4){0.f,0.f,0.f,0.f};
            cz[i] = (f32x4){0.f,0.f,0.f,0.f};
            cn[i] = (f32x4){0.f,0.f,0.f,0.f};
        }
#pragma unroll
        for (int kk = 0; kk < 8; ++kk) {
            bf16x8 a = *(const bf16x8*)&Ah[cl][kk * 32 + lh * 8];
#pragma unroll
            for (int ji = 0; ji < 2; ++ji) {
                cr[ji] = mfma16(a, Br[ji][kk], cr[ji]);
                cz[ji] = mfma16(a, Bz[ji][kk], cz[ji]);
                cn[ji] = mfma16(a, Bn[ji][kk], cn[ji]);
            }
        }
        // gx loads (issued pre-barrier; latency overlaps barrier wait)
        float gr[2][4], gz[2][4], gn[2][4];
#pragma unroll
        for (int ji = 0; ji < 2; ++ji) {
            const int col = (2 * w + ji) * 16 + cl;
#pragma unroll
            for (int r = 0; r < 4; ++r) {
                const size_t ro = (size_t)t * BB + g * 16 + 4 * lh + r;
                gr[ji][r] = (float)gxrz[ro * 512 + col];
                gz[ji][r] = (float)gxrz[ro * 512 + 256 + col];
                gn[ji][r] = gxn[ro * 256 + col];
            }
        }
        __syncthreads();   // all waves done reading Ah
#pragma unroll
        for (int ji = 0; ji < 2; ++ji) {
            const int col = (2 * w + ji) * 16 + cl;
#pragma unroll
            for (int r = 0; r < 4; ++r) {
                const int m = 4 * lh + r;
                float rr = sigf(gr[ji][r] + cr[ji][r] + bR[ji]);
                float zz = sigf(gz[ji][r] + cz[ji][r] + bZ[ji]);
                float nn = tanhfast(gn[ji][r] + rr * (cn[ji][r] + bN[ji]));
                float hnew = (1.f - zz) * nn + zz * hprev[ji][r];
                hprev[ji][r] = hnew;
                bf16 hb = (bf16)hnew;
                Ah[m][col] = hb;
                if (writeY) Y[((size_t)t * BB + g * 16 + m) * 256 + col] = hb;
                if (t == TT - 1) hnfL[(size_t)(g * 16 + m) * 768 + col] = hnew;
            }
        }
        __syncthreads();   // h writes visible before next step's GEMM
    }
}

// ---------------------------------------------------------------------------
// out[b][i] = fc_b[i] + dot(fc_w[i], hn[b])
// ---------------------------------------------------------------------------
__global__ __launch_bounds__(256) void fc_out(const float* __restrict__ hn,
                                              const float* __restrict__ fcw,
                                              const float* __restrict__ fcb,
                                              float* __restrict__ out)
{
    __shared__ float hs[768];
    const int b = blockIdx.x;
    for (int i = threadIdx.x; i < 768; i += 256) hs[i] = hn[(size_t)b * 768 + i];
    __syncthreads();
    for (int i = threadIdx.x; i < H_IN; i += 256) {
        const float4* wr = (const float4*)(fcw + (size_t)i * 768);
        float a0 = 0.f, a1 = 0.f, a2 = 0.f, a3 = 0.f;
#pragma unroll 4
        for (int c = 0; c < 192; ++c) {
            float4 wv = wr[c];
            const float* h4 = &hs[c * 4];
            a0 += wv.x * h4[0]; a1 += wv.y * h4[1];
            a2 += wv.z * h4[2]; a3 += wv.w * h4[3];
        }
        out[(size_t)b * H_IN + i] = fcb[i] + a0 + a1 + a2 + a3;
    }
}

extern "C" void kernel_launch(void* const* d_in, const int* in_sizes, int n_in,
                              void* d_out, int out_size, void* d_ws, size_t ws_size,
                              hipStream_t stream) {
    const float* X    = (const float*)d_in[0];
    const float* hid  = (const float*)d_in[1];
    const float* wih0 = (const float*)d_in[2];
    const float* whh0 = (const float*)d_in[3];
    const float* bih0 = (const float*)d_in[4];
    const float* bhh0 = (const float*)d_in[5];
    const float* wih1 = (const float*)d_in[6];
    const float* whh1 = (const float*)d_in[7];
    const float* bih1 = (const float*)d_in[8];
    const float* bhh1 = (const float*)d_in[9];
    const float* wih2 = (const float*)d_in[10];
    const float* whh2 = (const float*)d_in[11];
    const float* bih2 = (const float*)d_in[12];
    const float* bhh2 = (const float*)d_in[13];
    const float* fcw  = (const float*)d_in[14];
    const float* fcb  = (const float*)d_in[15];
    float* out = (float*)d_out;

    // Layout (total 43,525,120 B — well within the known-safe 52.7 MB):
    char* ws = (char*)d_ws;
    bf16*  Wh   = (bf16*)ws;                       //          0 .. 1,179,648
    float* bp   = (float*)(ws + 1179648);          //  1,179,648 .. 1,188,864
    float* hnf  = (float*)(ws + 1188864);          //  1,188,864 .. 1,582,080
    bf16*  Y    = (bf16*)(ws + 1582080);           //  1,582,080 .. 9,970,688
    float* gxn  = (float*)(ws + 9970688);          //  9,970,688 .. 26,747,904
    fp16*  gxrz = (fp16*)(ws + 26747904);          // 26,747,904 .. 43,525,120

    prep_pack2<<<dim3(1157), dim3(512), 0, stream>>>(whh0, whh1, whh2,
                                                     bhh0, bhh1, bhh2, Wh, bp);
    // layer 0
    gemm_gx0<<<dim3(128, 3), dim3(512), 0, stream>>>(X, wih0, bih0, gxrz, gxn);
    gru_rec<<<dim3(8), dim3(512), 0, stream>>>(gxrz, gxn, Wh, bp,
                                               hid, Y, 1, hnf);
    // layer 1
    gemm_gxy<<<dim3(128, 3), dim3(512), 0, stream>>>(Y, wih1, bih1, gxrz, gxn);
    gru_rec<<<dim3(8), dim3(512), 0, stream>>>(gxrz, gxn, Wh + 196608, bp + 768,
                                               hid + 32768, Y, 1, hnf + 256);
    // layer 2
    gemm_gxy<<<dim3(128, 3), dim3(512), 0, stream>>>(Y, wih2, bih2, gxrz, gxn);
    gru_rec<<<dim3(8), dim3(512), 0, stream>>>(gxrz, gxn, Wh + 393216, bp + 1536,
                                               hid + 65536, Y, 0, hnf + 512);
    // head
    fc_out<<<dim3(128), dim3(256), 0, stream>>>(hnf, fcw, fcb, out);
    hipMemcpyAsync(out + 171776, hid, 98304 * sizeof(float),
                   hipMemcpyDeviceToDevice, stream);
}